// Round 1
// baseline (208.365 us; speedup 1.0000x reference)
//
#include <hip/hip_runtime.h>
#include <hip/hip_bf16.h>
#include <stdint.h>

// Problem constants (fixed by the reference)
#define NB   2
#define SEQ  2048
#define EMB  1024
#define NH   16
#define DH   64
#define MR   (NB*SEQ)   // 4096 total rows
#define E3   (3*EMB)    // 3072
#define L2E  1.44269504f

typedef __attribute__((ext_vector_type(8))) short bf16x8;
typedef __attribute__((ext_vector_type(4))) float f32x4;

__device__ __forceinline__ unsigned short f2bf(float f) {
  unsigned u = __float_as_uint(f);
  unsigned r = (u + 0x7FFF + ((u >> 16) & 1)) >> 16;   // RNE
  return (unsigned short)r;
}
__device__ __forceinline__ float bf2f(unsigned short s) {
  return __uint_as_float(((unsigned)s) << 16);
}

__device__ __forceinline__ void gld16(const unsigned short* g, unsigned short* l) {
  __builtin_amdgcn_global_load_lds(
      (const __attribute__((address_space(1))) unsigned int*)g,
      (__attribute__((address_space(3))) unsigned int*)l,
      16, 0, 0);
}

// ---------------- fp32 -> bf16 convert ----------------
__global__ void cvt_f32_bf16(const float* __restrict__ in,
                             unsigned short* __restrict__ out, int n) {
  int i = (blockIdx.x * 256 + threadIdx.x) * 8;
  if (i >= n) return;
  float4 a = *(const float4*)(in + i);
  float4 b = *(const float4*)(in + i + 4);
  uint4 o;
  o.x = (unsigned)f2bf(a.x) | ((unsigned)f2bf(a.y) << 16);
  o.y = (unsigned)f2bf(a.z) | ((unsigned)f2bf(a.w) << 16);
  o.z = (unsigned)f2bf(b.x) | ((unsigned)f2bf(b.y) << 16);
  o.w = (unsigned)f2bf(b.z) | ((unsigned)f2bf(b.w) << 16);
  *(uint4*)(out + i) = o;
}

// ---------------- GEMM: C[M][N] = A[M][K] * Bt[N][K]^T + bias ----------------
// 128x128 tile, BK=32, 4 waves (2x2), 16x16x32 bf16 MFMA (m97 structure).
template<bool OUT_F32>
__global__ __launch_bounds__(256) void gemm_bt(
    const unsigned short* __restrict__ A,
    const unsigned short* __restrict__ Bt,
    const float* __restrict__ bias,
    void* __restrict__ Cout,
    int K, int ldc) {
  __shared__ unsigned short As[4096];  // [128][32]
  __shared__ unsigned short Bs[4096];  // [128][32]
  const int tid  = threadIdx.x;
  const int lane = tid & 63;
  const int w    = tid >> 6;
  const int wm = w >> 1, wn = w & 1;
  const int g = lane >> 4, li = lane & 15;
  const int rowBase = blockIdx.x * 128;
  const int colBase = blockIdx.y * 128;

  f32x4 acc[4][4];
#pragma unroll
  for (int m = 0; m < 4; ++m)
#pragma unroll
    for (int nn = 0; nn < 4; ++nn) { acc[m][nn][0]=0.f; acc[m][nn][1]=0.f; acc[m][nn][2]=0.f; acc[m][nn][3]=0.f; }

  const unsigned short* Ag = A  + (size_t)(rowBase + (tid >> 2)) * K + (tid & 3) * 8;
  const unsigned short* Bg = Bt + (size_t)(colBase + (tid >> 2)) * K + (tid & 3) * 8;

  for (int k0 = 0; k0 < K; k0 += 32) {
    __syncthreads();                       // protect LDS from prior-iter readers
    gld16(Ag + k0,                As + tid * 8);
    gld16(Ag + (size_t)64*K + k0, As + 2048 + tid * 8);
    gld16(Bg + k0,                Bs + tid * 8);
    gld16(Bg + (size_t)64*K + k0, Bs + 2048 + tid * 8);
    __syncthreads();                       // barrier drains vmcnt -> LDS ready

    bf16x8 af[4], bfv[4];
#pragma unroll
    for (int m = 0; m < 4; ++m)
      af[m] = *(const bf16x8*)&As[(wm*64 + m*16 + li) * 32 + g * 8];
#pragma unroll
    for (int nn = 0; nn < 4; ++nn)
      bfv[nn] = *(const bf16x8*)&Bs[(wn*64 + nn*16 + li) * 32 + g * 8];
#pragma unroll
    for (int m = 0; m < 4; ++m)
#pragma unroll
      for (int nn = 0; nn < 4; ++nn)
        acc[m][nn] = __builtin_amdgcn_mfma_f32_16x16x32_bf16(af[m], bfv[nn], acc[m][nn], 0, 0, 0);
  }

#pragma unroll
  for (int nn = 0; nn < 4; ++nn) {
    const int col = colBase + wn*64 + nn*16 + li;
    const float bv = bias[col];
#pragma unroll
    for (int m = 0; m < 4; ++m) {
      const int r0 = rowBase + wm*64 + m*16 + g*4;
#pragma unroll
      for (int r = 0; r < 4; ++r) {
        float v = acc[m][nn][r] + bv;
        if (OUT_F32) ((float*)Cout)[(size_t)(r0 + r) * ldc + col] = v;
        else ((unsigned short*)Cout)[(size_t)(r0 + r) * ldc + col] = f2bf(v);
      }
    }
  }
}

// ---------------- Flash attention ----------------
// block = (n, h, 64 q-rows); 4 waves x 16 q-rows each. 64-key tiles.
// K LDS [64key][64k] XOR-swizzled; V LDS stored TRANSPOSED [64d][64key] XOR-swizzled;
// P bounced via per-wave swizzled LDS. Online softmax in exp2 domain.
__global__ __launch_bounds__(256) void attn_kernel(
    const unsigned short* __restrict__ qkv,   // [4096][3072] bf16: q|k|v
    unsigned short* __restrict__ x2) {        // [4096][1024] bf16
  __shared__ unsigned short Ks[4096];    // 8 KB
  __shared__ unsigned short Vts[4096];   // 8 KB
  __shared__ unsigned short Ps[4][1024]; // 4 x 2 KB

  const int tid  = threadIdx.x;
  const int lane = tid & 63;
  const int w    = tid >> 6;
  const int g = lane >> 4, li = lane & 15;
  const int b  = blockIdx.x;
  const int qt = b & 31;
  const int h  = (b >> 5) & 15;
  const int n  = b >> 9;

  // Q fragments, pre-scaled by exact 1/sqrt(Dh)=0.125 (power of 2: exact in bf16)
  const size_t qrow = (size_t)n * SEQ + qt * 64 + w * 16 + li;
  bf16x8 aq[2];
#pragma unroll
  for (int kk = 0; kk < 2; ++kk) {
    bf16x8 v = *(const bf16x8*)&qkv[qrow * E3 + h * 64 + kk * 32 + g * 8];
#pragma unroll
    for (int j = 0; j < 8; ++j)
      v[j] = (short)f2bf(bf2f((unsigned short)v[j]) * 0.125f);
    aq[kk] = v;
  }

  float m_old[4], lsum[4];
  f32x4 acc[4];
#pragma unroll
  for (int r = 0; r < 4; ++r) { m_old[r] = -__builtin_inff(); lsum[r] = 0.f; }
#pragma unroll
  for (int nt = 0; nt < 4; ++nt) { acc[nt][0]=0.f; acc[nt][1]=0.f; acc[nt][2]=0.f; acc[nt][3]=0.f; }

  const int vp_ = tid & 31, dblk = tid >> 5;   // V staging mapping (bank-bijective)

  for (int kt = 0; kt < SEQ; kt += 64) {
    __syncthreads();   // prior tile fully consumed
    // ---- stage K [64key][64], swizzled: chunk ^= row&7 ----
#pragma unroll
    for (int cc = 0; cc < 2; ++cc) {
      int c = tid + cc * 256;
      int r = c >> 3, cb = c & 7;
      uint4 d = *(const uint4*)&qkv[((size_t)n*SEQ + kt + r) * E3 + EMB + h*64 + cb*8];
      *(uint4*)((char*)Ks + r * 128 + ((cb ^ (r & 7)) << 4)) = d;
    }
    // ---- stage V transposed -> Vts[64d][64key], key-pairs packed b32 ----
    {
      const unsigned short* vp = &qkv[((size_t)n*SEQ + kt + 2*vp_) * E3 + 2*EMB + h*64 + dblk*8];
      uint4 v0 = *(const uint4*)vp;
      uint4 v1 = *(const uint4*)(vp + E3);
      const unsigned short* s0 = (const unsigned short*)&v0;
      const unsigned short* s1 = (const unsigned short*)&v1;
#pragma unroll
      for (int j = 0; j < 8; ++j) {
        int d = dblk * 8 + j;
        unsigned val = (unsigned)s0[j] | ((unsigned)s1[j] << 16);
        *(unsigned*)((char*)Vts + d * 128 + (((vp_ >> 2) ^ (d & 7)) << 4) + (vp_ & 3) * 4) = val;
      }
    }
    __syncthreads();

    // ---- scores: 16q x 64key, QK^T via 8 MFMA ----
    f32x4 sc[4];
#pragma unroll
    for (int c = 0; c < 4; ++c) {
      int row = c * 16 + li;
      bf16x8 bk0 = *(const bf16x8*)((char*)Ks + row * 128 + (((0 + g) ^ (row & 7)) << 4));
      bf16x8 bk1 = *(const bf16x8*)((char*)Ks + row * 128 + (((4 + g) ^ (row & 7)) << 4));
      f32x4 z; z[0]=0.f; z[1]=0.f; z[2]=0.f; z[3]=0.f;
      z = __builtin_amdgcn_mfma_f32_16x16x32_bf16(aq[0], bk0, z, 0, 0, 0);
      z = __builtin_amdgcn_mfma_f32_16x16x32_bf16(aq[1], bk1, z, 0, 0, 0);
      sc[c] = z;
    }

    // ---- online softmax (exp2 domain); lane holds rows g*4+r, key c*16+li ----
    float pr[4][4];
#pragma unroll
    for (int r = 0; r < 4; ++r) {
      float t0 = sc[0][r] * L2E, t1 = sc[1][r] * L2E, t2 = sc[2][r] * L2E, t3 = sc[3][r] * L2E;
      float tm = fmaxf(fmaxf(t0, t1), fmaxf(t2, t3));
      tm = fmaxf(tm, __shfl_xor(tm, 1));
      tm = fmaxf(tm, __shfl_xor(tm, 2));
      tm = fmaxf(tm, __shfl_xor(tm, 4));
      tm = fmaxf(tm, __shfl_xor(tm, 8));
      float mn = fmaxf(m_old[r], tm);
      float scale = exp2f(m_old[r] - mn);
      float p0 = exp2f(t0 - mn), p1 = exp2f(t1 - mn), p2 = exp2f(t2 - mn), p3 = exp2f(t3 - mn);
      float ps = p0 + p1 + p2 + p3;
      ps += __shfl_xor(ps, 1);
      ps += __shfl_xor(ps, 2);
      ps += __shfl_xor(ps, 4);
      ps += __shfl_xor(ps, 8);
      lsum[r] = lsum[r] * scale + ps;
      m_old[r] = mn;
      pr[0][r] = p0; pr[1][r] = p1; pr[2][r] = p2; pr[3][r] = p3;
#pragma unroll
      for (int nt = 0; nt < 4; ++nt) acc[nt][r] *= scale;
    }

    // ---- write P (bf16) to per-wave swizzled LDS ----
#pragma unroll
    for (int c = 0; c < 4; ++c) {
      int key = c * 16 + li;
#pragma unroll
      for (int r = 0; r < 4; ++r) {
        int row = g * 4 + r;
        *(unsigned short*)((char*)&Ps[w][0] + row * 128 + ((((key >> 3) ^ (row & 7))) << 4) + (key & 7) * 2)
            = f2bf(pr[c][r]);
      }
    }
    asm volatile("s_waitcnt lgkmcnt(0)" ::: "memory");  // within-wave RAW through LDS

    // ---- PV: acc += P(16x64) * V(64x64) via 8 MFMA ----
    bf16x8 ap[2];
#pragma unroll
    for (int kk = 0; kk < 2; ++kk)
      ap[kk] = *(const bf16x8*)((char*)&Ps[w][0] + li * 128 + (((kk*4 + g) ^ (li & 7)) << 4));
#pragma unroll
    for (int nt = 0; nt < 4; ++nt) {
      int d = nt * 16 + li;
#pragma unroll
      for (int kk = 0; kk < 2; ++kk) {
        bf16x8 bv = *(const bf16x8*)((char*)Vts + d * 128 + (((kk*4 + g) ^ (d & 7)) << 4));
        acc[nt] = __builtin_amdgcn_mfma_f32_16x16x32_bf16(ap[kk], bv, acc[nt], 0, 0, 0);
      }
    }
  }

  // ---- epilogue: normalize, write bf16 attn output [4096][1024] ----
#pragma unroll
  for (int nt = 0; nt < 4; ++nt) {
    int col = h * 64 + nt * 16 + li;
#pragma unroll
    for (int r = 0; r < 4; ++r) {
      size_t row = (size_t)n * SEQ + qt * 64 + w * 16 + g * 4 + r;
      x2[row * EMB + col] = f2bf(acc[nt][r] / lsum[r]);
    }
  }
}

// ---------------- launch ----------------
extern "C" void kernel_launch(void* const* d_in, const int* in_sizes, int n_in,
                              void* d_out, int out_size, void* d_ws, size_t ws_size,
                              hipStream_t stream) {
  const float* q    = (const float*)d_in[0];
  // d_in[1] (key) and d_in[2] (value) are ignored by the reference's math.
  const float* w_in = (const float*)d_in[3];
  const float* b_in = (const float*)d_in[4];
  const float* w_o  = (const float*)d_in[5];
  const float* b_o  = (const float*)d_in[6];

  char* ws = (char*)d_ws;
  // ws layout (needs ~48 MB)
  unsigned short* Xbf   = (unsigned short*)(ws);                 // 4096x1024
  unsigned short* Winbf = (unsigned short*)(ws + 8388608);       // 3072x1024
  unsigned short* Wobf  = (unsigned short*)(ws + 14680064);      // 1024x1024
  unsigned short* QKV   = (unsigned short*)(ws + 16777216);      // 4096x3072
  unsigned short* X2    = (unsigned short*)(ws + 41943040);      // 4096x1024

  cvt_f32_bf16<<<2048, 256, 0, stream>>>(q,    Xbf,   MR * EMB);
  cvt_f32_bf16<<<1536, 256, 0, stream>>>(w_in, Winbf, E3 * EMB);
  cvt_f32_bf16<<<512,  256, 0, stream>>>(w_o,  Wobf,  EMB * EMB);

  // QKV projection: [4096][3072] = X * w_in^T + b_in
  gemm_bt<false><<<dim3(32, 24), 256, 0, stream>>>(Xbf, Winbf, b_in, (void*)QKV, EMB, E3);
  // attention -> X2 [4096][1024]
  attn_kernel<<<NB * NH * (SEQ / 64), 256, 0, stream>>>(QKV, X2);
  // out projection: d_out fp32 [4096][1024] = X2 * w_o^T + b_o
  gemm_bt<true><<<dim3(32, 8), 256, 0, stream>>>(X2, Wobf, b_o, d_out, EMB, EMB);
}

// Round 5
// 163.420 us; speedup vs baseline: 1.2750x; 1.2750x over previous
//
#include <hip/hip_runtime.h>
#include <hip/hip_bf16.h>
#include <stdint.h>

#define NB   2
#define SEQ  2048
#define EMB  1024
#define NH   16
#define DH   64
#define MR   (NB*SEQ)   // 4096 rows
#define E3   (3*EMB)    // 3072

typedef __attribute__((ext_vector_type(8))) short bf16x8;
typedef __attribute__((ext_vector_type(4))) float f32x4;
typedef __attribute__((ext_vector_type(16))) float f32x16;

__device__ __forceinline__ unsigned short f2bf(float f) {
  unsigned u = __float_as_uint(f);
  unsigned r = (u + 0x7FFF + ((u >> 16) & 1)) >> 16;   // RNE
  return (unsigned short)r;
}
__device__ __forceinline__ unsigned pack2(float lo, float hi) {  // RNE bf16 pair
  return (unsigned)f2bf(lo) | ((unsigned)f2bf(hi) << 16);
}

__device__ __forceinline__ void gld16(const unsigned short* g, unsigned short* l) {
  __builtin_amdgcn_global_load_lds(
      (const __attribute__((address_space(1))) unsigned int*)g,
      (__attribute__((address_space(3))) unsigned int*)l,
      16, 0, 0);
}

// ---------------- fp32 -> bf16 convert ----------------
__global__ void cvt_f32_bf16(const float* __restrict__ in,
                             unsigned short* __restrict__ out, int n) {
  int i = (blockIdx.x * 256 + threadIdx.x) * 8;
  if (i >= n) return;
  float4 a = *(const float4*)(in + i);
  float4 b = *(const float4*)(in + i + 4);
  uint4 o;
  o.x = pack2(a.x, a.y);
  o.y = pack2(a.z, a.w);
  o.z = pack2(b.x, b.y);
  o.w = pack2(b.z, b.w);
  *(uint4*)(out + i) = o;
}

// ---------------- GEMM: C[M][N] = A[M][K] * Bt[N][K]^T + bias ----------------
template<bool OUT_F32>
__global__ __launch_bounds__(256) void gemm_bt(
    const unsigned short* __restrict__ A,
    const unsigned short* __restrict__ Bt,
    const float* __restrict__ bias,
    void* __restrict__ Cout,
    int K, int ldc) {
  __shared__ unsigned short As[4096];
  __shared__ unsigned short Bs[4096];
  const int tid  = threadIdx.x;
  const int lane = tid & 63;
  const int w    = tid >> 6;
  const int wm = w >> 1, wn = w & 1;
  const int g = lane >> 4, li = lane & 15;
  const int rowBase = blockIdx.x * 128;
  const int colBase = blockIdx.y * 128;

  f32x4 acc[4][4];
#pragma unroll
  for (int m = 0; m < 4; ++m)
#pragma unroll
    for (int nn = 0; nn < 4; ++nn) { acc[m][nn][0]=0.f; acc[m][nn][1]=0.f; acc[m][nn][2]=0.f; acc[m][nn][3]=0.f; }

  const unsigned short* Ag = A  + (size_t)(rowBase + (tid >> 2)) * K + (tid & 3) * 8;
  const unsigned short* Bg = Bt + (size_t)(colBase + (tid >> 2)) * K + (tid & 3) * 8;

  for (int k0 = 0; k0 < K; k0 += 32) {
    __syncthreads();
    gld16(Ag + k0,                As + tid * 8);
    gld16(Ag + (size_t)64*K + k0, As + 2048 + tid * 8);
    gld16(Bg + k0,                Bs + tid * 8);
    gld16(Bg + (size_t)64*K + k0, Bs + 2048 + tid * 8);
    __syncthreads();

    bf16x8 af[4], bfv[4];
#pragma unroll
    for (int m = 0; m < 4; ++m)
      af[m] = *(const bf16x8*)&As[(wm*64 + m*16 + li) * 32 + g * 8];
#pragma unroll
    for (int nn = 0; nn < 4; ++nn)
      bfv[nn] = *(const bf16x8*)&Bs[(wn*64 + nn*16 + li) * 32 + g * 8];
#pragma unroll
    for (int m = 0; m < 4; ++m)
#pragma unroll
      for (int nn = 0; nn < 4; ++nn)
        acc[m][nn] = __builtin_amdgcn_mfma_f32_16x16x32_bf16(af[m], bfv[nn], acc[m][nn], 0, 0, 0);
  }

#pragma unroll
  for (int nn = 0; nn < 4; ++nn) {
    const int col = colBase + wn*64 + nn*16 + li;
    const float bv = bias[col];
#pragma unroll
    for (int m = 0; m < 4; ++m) {
      const int r0 = rowBase + wm*64 + m*16 + g*4;
#pragma unroll
      for (int r = 0; r < 4; ++r) {
        float v = acc[m][nn][r] + bv;
        if (OUT_F32) ((float*)Cout)[(size_t)(r0 + r) * ldc + col] = v;
        else ((unsigned short*)Cout)[(size_t)(r0 + r) * ldc + col] = f2bf(v);
      }
    }
  }
}

// ---------------- Flash attention, 32x32 MFMA, swapped operands ----------------
// block = (n, h, 128 q-rows); 4 waves x 32 q-rows. 64-key tiles, K/V double-buffered.
// QK^T computed as Z = mfma(K, Q) -> lane owns all scores of q = lane&31.
// PV computed as O^T = mfma(V^T, P) -> acc col = q stays lane-local.
// NO inline-asm cross-lane ops: __shfl_xor (ds_bpermute) only.
__global__ __launch_bounds__(256) void attn32(
    const unsigned short* __restrict__ qkv,   // [4096][3072] bf16: q|k|v
    unsigned short* __restrict__ x2) {        // [4096][1024] bf16
  __shared__ unsigned short smem[16384];      // 32KB: Ks[2]@0/8KB, Vts[2]@16/24KB
  char* LB = (char*)smem;

  const int tid  = threadIdx.x;
  const int lane = tid & 63;
  const int w    = tid >> 6;
  const int hi   = lane >> 5;
  const int l31  = lane & 31;
  const int bid  = blockIdx.x;
  const int qb = bid & 15, h = (bid >> 4) & 15, n = bid >> 8;
  const size_t rowN = (size_t)n * SEQ;
  const int vp_ = tid & 31, dblk = tid >> 5;
  const float CS = 0.125f * 1.44269504f;   // scale * log2(e)

  // ---- Q fragments (regs, hoisted): Q[q=l31][kc*16 + hi*8 + j] ----
  bf16x8 qf[4];
  {
    const size_t qr = rowN + qb*128 + w*32 + l31;
#pragma unroll
    for (int kc = 0; kc < 4; ++kc)
      qf[kc] = *(const bf16x8*)&qkv[qr * E3 + h*64 + kc*16 + hi*8];
  }

  f32x16 ZEROV;
#pragma unroll
  for (int i = 0; i < 16; ++i) ZEROV[i] = 0.f;
  f32x16 acc0 = ZEROV, acc1 = ZEROV;   // O^T: d = dt*32 + crow(r,hi), q = l31
  float m = -__builtin_inff(), lsum = 0.f;

  uint4 pv0, pv1;
  auto stageK = [&](int kt, int buf) {
#pragma unroll
    for (int p = 0; p < 2; ++p) {
      int r = p*32 + (tid >> 3);
      int ch = (tid & 7) ^ (r & 7);
      gld16(&qkv[(rowN + kt + r) * E3 + EMB + h*64 + ch*8],
            &smem[buf*4096 + p*2048 + tid*8]);
    }
  };
  auto loadV = [&](int kt) {
    const unsigned short* vp = &qkv[(rowN + kt + 2*vp_) * E3 + 2*EMB + h*64 + dblk*8];
    pv0 = *(const uint4*)vp;
    pv1 = *(const uint4*)(vp + E3);
  };
  auto writeV = [&](int buf) {
    const unsigned short* s0 = (const unsigned short*)&pv0;
    const unsigned short* s1 = (const unsigned short*)&pv1;
#pragma unroll
    for (int j = 0; j < 8; ++j) {
      int d = dblk*8 + j;
      unsigned val = (unsigned)s0[j] | ((unsigned)s1[j] << 16);
      *(unsigned*)(LB + 16384 + buf*8192 + d*128 + (((vp_>>2) ^ (d&7)) << 4) + (vp_&3)*4) = val;
    }
  };
  // P -> bf16 B-fragment via shfl_xor(32) + select (no permlane asm).
  // Key-ownership: own a=pack(z0,z1) keys crow(0..1,hi); b keys crow(2..3,hi);
  // c=pack(z4,z5) keys crow(4..5,hi); d keys crow(6..7,hi).
  // u0 = hi? xc : a ; u1 = hi? xd : b ; u2 = hi? c : xa ; u3 = hi? d : xb.
  auto mkfrag = [&](float a0, float a1, float a2, float a3,
                    float a4, float a5, float a6, float a7) {
    unsigned a = pack2(a0, a1);
    unsigned b = pack2(a2, a3);
    unsigned c = pack2(a4, a5);
    unsigned d = pack2(a6, a7);
    unsigned xa = __shfl_xor(a, 32);
    unsigned xb = __shfl_xor(b, 32);
    unsigned xc = __shfl_xor(c, 32);
    unsigned xd = __shfl_xor(d, 32);
    union { bf16x8 v; unsigned u[4]; } r;
    r.u[0] = hi ? xc : a;
    r.u[1] = hi ? xd : b;
    r.u[2] = hi ? c : xa;
    r.u[3] = hi ? d : xb;
    return r.v;
  };

  loadV(0);
  stageK(0, 0);
  writeV(0);
  __syncthreads();

  for (int t = 0; t < SEQ/64; ++t) {
    const int cur = t & 1;
    const bool pre = (t + 1 < SEQ/64);
    if (pre) { loadV((t+1)*64); stageK((t+1)*64, cur^1); }  // overlap with compute

    // ---- QK^T: Z[key][q], two 32-key blocks ----
    const char* Kb = LB + cur*8192;
    bf16x8 ka[4], kb[4];
#pragma unroll
    for (int kc = 0; kc < 4; ++kc) {
      int ch = kc*2 + hi;
      int sw = (ch ^ (l31 & 7)) << 4;
      ka[kc] = *(const bf16x8*)(Kb + l31*128 + sw);
      kb[kc] = *(const bf16x8*)(Kb + 4096 + l31*128 + sw);
    }
    __builtin_amdgcn_s_setprio(1);
    f32x16 z0 = __builtin_amdgcn_mfma_f32_32x32x16_bf16(ka[0], qf[0], ZEROV, 0, 0, 0);
    f32x16 z1 = __builtin_amdgcn_mfma_f32_32x32x16_bf16(kb[0], qf[0], ZEROV, 0, 0, 0);
#pragma unroll
    for (int kc = 1; kc < 4; ++kc) {
      z0 = __builtin_amdgcn_mfma_f32_32x32x16_bf16(ka[kc], qf[kc], z0, 0, 0, 0);
      z1 = __builtin_amdgcn_mfma_f32_32x32x16_bf16(kb[kc], qf[kc], z1, 0, 0, 0);
    }
    __builtin_amdgcn_s_setprio(0);

    // ---- online softmax in exp2 domain, lane-local for q = l31 ----
    float mx[16];
#pragma unroll
    for (int i = 0; i < 16; ++i) mx[i] = fmaxf(z0[i], z1[i]);
#pragma unroll
    for (int st = 8; st; st >>= 1)
#pragma unroll
      for (int i = 0; i < st; ++i) mx[i] = fmaxf(mx[i], mx[i + st]);
    float tm = fmaxf(mx[0], __shfl_xor(mx[0], 32));

    // unconditional rescale
    {
      float mn = fmaxf(m, tm);
      float sc = __builtin_amdgcn_exp2f((m - mn) * CS);
#pragma unroll
      for (int i = 0; i < 16; ++i) { acc0[i] *= sc; acc1[i] *= sc; }
      lsum *= sc;
      m = mn;
    }
    const float mC = m * CS;
#pragma unroll
    for (int i = 0; i < 16; ++i) {
      z0[i] = __builtin_amdgcn_exp2f(fmaf(z0[i], CS, -mC));
      z1[i] = __builtin_amdgcn_exp2f(fmaf(z1[i], CS, -mC));
    }
    float sA[8];
#pragma unroll
    for (int i = 0; i < 8; ++i) sA[i] = (z0[2*i] + z0[2*i+1]) + (z1[2*i] + z1[2*i+1]);
#pragma unroll
    for (int st = 4; st; st >>= 1)
#pragma unroll
      for (int i = 0; i < st; ++i) sA[i] += sA[i + st];
    lsum += sA[0] + __shfl_xor(sA[0], 32);

    // ---- P -> bf16 B-fragments in registers ----
    bf16x8 pf[4];
    pf[0] = mkfrag(z0[0], z0[1], z0[2],  z0[3],  z0[4],  z0[5],  z0[6],  z0[7]);
    pf[1] = mkfrag(z0[8], z0[9], z0[10], z0[11], z0[12], z0[13], z0[14], z0[15]);
    pf[2] = mkfrag(z1[0], z1[1], z1[2],  z1[3],  z1[4],  z1[5],  z1[6],  z1[7]);
    pf[3] = mkfrag(z1[8], z1[9], z1[10], z1[11], z1[12], z1[13], z1[14], z1[15]);

    if (pre) writeV(cur ^ 1);   // V regs ready by now; hides under softmax

    // ---- PV: O^T += V^T * P ----
    const char* Vb = LB + 16384 + cur*8192;
    __builtin_amdgcn_s_setprio(1);
#pragma unroll
    for (int c = 0; c < 4; ++c) {
      int ch = c*2 + hi;
      int sw = (ch ^ (l31 & 7)) << 4;
      bf16x8 va = *(const bf16x8*)(Vb + l31*128 + sw);
      bf16x8 vb = *(const bf16x8*)(Vb + 4096 + l31*128 + sw);
      acc0 = __builtin_amdgcn_mfma_f32_32x32x16_bf16(va, pf[c], acc0, 0, 0, 0);
      acc1 = __builtin_amdgcn_mfma_f32_32x32x16_bf16(vb, pf[c], acc1, 0, 0, 0);
    }
    __builtin_amdgcn_s_setprio(0);
    __syncthreads();
  }

  // ---- epilogue: normalize (IEEE), transpose via LDS, coalesced store ----
  float rn = 1.0f / lsum;
  const int qrow_l = w*32 + l31;
#pragma unroll
  for (int dt = 0; dt < 2; ++dt) {
#pragma unroll
    for (int r = 0; r < 16; r += 2) {
      float v0 = (dt ? acc1[r]   : acc0[r])   * rn;
      float v1 = (dt ? acc1[r+1] : acc0[r+1]) * rn;
      int d = dt*32 + (r & 3) + 8*(r >> 2) + 4*hi;
      unsigned val = pack2(v0, v1);
      int col32 = d >> 1;
      int g = col32 >> 2;
      *(unsigned*)(LB + qrow_l*128 + ((g ^ (qrow_l & 7)) << 4) + (col32 & 3)*4) = val;
    }
  }
  __syncthreads();
  {
    int row = tid >> 1;
    size_t orow = (rowN + qb*128 + row) * EMB + h*64;
#pragma unroll
    for (int i = 0; i < 4; ++i) {
      int gg = (tid & 1)*4 + i;
      uint4 v = *(const uint4*)(LB + row*128 + ((gg ^ (row & 7)) << 4));
      *(uint4*)&x2[orow + gg*8] = v;
    }
  }
}

// ---------------- launch ----------------
extern "C" void kernel_launch(void* const* d_in, const int* in_sizes, int n_in,
                              void* d_out, int out_size, void* d_ws, size_t ws_size,
                              hipStream_t stream) {
  const float* q    = (const float*)d_in[0];
  const float* w_in = (const float*)d_in[3];
  const float* b_in = (const float*)d_in[4];
  const float* w_o  = (const float*)d_in[5];
  const float* b_o  = (const float*)d_in[6];

  char* ws = (char*)d_ws;
  unsigned short* Xbf   = (unsigned short*)(ws);                 // 4096x1024
  unsigned short* Winbf = (unsigned short*)(ws + 8388608);       // 3072x1024
  unsigned short* Wobf  = (unsigned short*)(ws + 14680064);      // 1024x1024
  unsigned short* QKV   = (unsigned short*)(ws + 16777216);      // 4096x3072
  unsigned short* X2    = (unsigned short*)(ws + 41943040);      // 4096x1024

  cvt_f32_bf16<<<2048, 256, 0, stream>>>(q,    Xbf,   MR * EMB);
  cvt_f32_bf16<<<1536, 256, 0, stream>>>(w_in, Winbf, E3 * EMB);
  cvt_f32_bf16<<<512,  256, 0, stream>>>(w_o,  Wobf,  EMB * EMB);

  gemm_bt<false><<<dim3(32, 24), 256, 0, stream>>>(Xbf, Winbf, b_in, (void*)QKV, EMB, E3);
  attn32<<<NB * NH * (SEQ / 128), 256, 0, stream>>>(QKV, X2);
  gemm_bt<true><<<dim3(32, 8), 256, 0, stream>>>(X2, Wobf, b_o, d_out, EMB, EMB);
}